// Round 12
// baseline (279.993 us; speedup 1.0000x reference)
//
#include <hip/hip_runtime.h>

// LSTM: B=2048, T=512, D=1, H=50, OUT=3, fp32.
//
// R13: contiguous B layout + NW=8 x 2 tiles. History (dispatch us):
//  R1-R4 582..539 VALU-bound; R5 381; R6 291 (NW13 fused); R7 345 (NW8,
//  fat tails); R8 268.6 (fp16 2-term); R9 269 (null); R10 316 (NW4);
//  R11 FAIL (aug clobber); R12 214.5 (K-aug + prescale + NW16 balance).
// R12 decomposition (step 1006 cyc): LDS ~550 (32 redundant b128 reads
//  ~384 + conflicts 156 + writes), VALU stack 314/SIMD, rest latency.
//
// R13 changes:
//  * Contiguous fragment-order h layout: element (k, batch b) at u16 idx
//    128*(k>>3) + 8*b + (k&7). Wave B0 read = bytes 16*lane of a 1KB
//    region (canonical conflict-free b128), B1 at +1KB. Read conflicts
//    -> ~0. Logical (k,b) convention UNCHANGED from R12 (verified).
//  * NW=8 waves, 2 tiles each (units 8w..8w+7; R10-verified 2-tile A
//    pattern): redundant reads 32 -> 16/step. Per-wave tail now small
//    (K-aug: no gate-init, no L-muls) -> stack ~260/SIMD ~= R12's 314.
//  * Wave 7 owns only pad units (no h-writes) -> it does the x/bias aug
//    writes (balance). Slot map: 61=x_lo', 62=1.0, 63=x_hi; (62,63)
//    packed as one b32 write, 1.0 refreshed each step.
//  * All else = R12: K-augmentation, L-prescale in A hi/lo, merged-rcp
//    cell, fp16 h, 1 barrier/step, guarded h-writes (u<50).
// Conventions (R5-R12 verified): A row=lane&15 (permuted gate=R&3,
// unit=4*tile+(R>>2)), k=8*(lane>>4)+e (+32/K-step); B col=lane&15,
// same k; D col=lane&15, row=4*(lane>>4)+reg.

#define BB 2048
#define TT 512
#define HH 50
#define NB 16            // batches per block (= MFMA cols)
#define NW 8             // waves; 2 tiles each -> 64 unit slots (50 real)
#define XP 513           // xs row stride (floats)
#define LO_SCALE  2048.0f            // 2^11
#define LO_ISCALE 0.00048828125f     // 2^-11
#define L1 -1.4426950408889634f      // -log2(e)
#define L2 -2.8853900817779268f      // -2*log2(e)

typedef __attribute__((ext_vector_type(4))) float    f32x4;
typedef __attribute__((ext_vector_type(8))) _Float16 f16x8;

#define F16BITS(v) __builtin_bit_cast(unsigned short, (_Float16)(v))

__global__ __launch_bounds__(NW * 64)
void lstm_r13_kernel(const float* __restrict__ x,
                     const float* __restrict__ W_ih,
                     const float* __restrict__ W_hh,
                     const float* __restrict__ b_ih,
                     const float* __restrict__ b_hh,
                     const float* __restrict__ fc_w,
                     const float* __restrict__ fc_b,
                     float* __restrict__ out) {
    __shared__ float xs[NB * XP];                      // 32.8 KB
    __shared__ __align__(16) unsigned short hb[2][1024];  // 4 KB, frag-order
    __shared__ float hfin[NB][64];                     // 4 KB

    const int tid  = threadIdx.x;
    const int w    = tid >> 6;          // wave id 0..7 (tiles 2w, 2w+1)
    const int lane = tid & 63;
    const int hi   = lane >> 4;
    const int bcol = lane & 15;         // batch column
    const int b0   = blockIdx.x * NB;

    // ---- stage x rows (coalesced) + zero pad col 512 ----
    for (int idx = tid; idx < NB * TT; idx += NW * 64) {
        xs[(idx >> 9) * XP + (idx & 511)] = x[(b0 + (idx >> 9)) * TT + (idx & 511)];
    }
    if (tid < NB) xs[tid * XP + 512] = 0.0f;
    // ---- zero h buffers (both; pad slots stay 0 forever) ----
    for (int idx = tid; idx < (int)(sizeof(hb) / 4); idx += NW * 64) {
        ((unsigned*)hb)[idx] = 0;
    }

    // ---- A-fragments for 2 tiles: permuted rows, L-prescaled, augmented ----
    // Tile tau = 2w+tt; lane supplies row R=lane&15: gate=R&3, unit=4tau+(R>>2).
    // k cols: [0,50)=Lg*W_hh hi/lo; 61: Al=Lg*W_ih (pairs x_lo'); 62: bias
    // hi/lo (pairs 1.0); 63: Lg*W_ih hi/lo (pairs x_hi).
    const int ga = bcol & 3;
    const int qa = bcol >> 2;
    const float Lg = (ga == 2) ? L2 : L1;
    f16x8 Ah[2][2], Al[2][2];           // [tile][K-step], const indices only
    #pragma unroll
    for (int tt = 0; tt < 2; ++tt) {
        const int ua = 8 * w + 4 * tt + qa;
        const bool ok = (ua < HH);
        #pragma unroll
        for (int s = 0; s < 2; ++s) {
            f16x8 vh = {}, vl = {};
            #pragma unroll
            for (int e = 0; e < 8; ++e) {
                const int k = 32 * s + 8 * hi + e;
                _Float16 ah = (_Float16)0.0f, al = (_Float16)0.0f;
                if (ok) {
                    if (k < HH) {
                        const float wv = Lg * W_hh[(ga * HH + ua) * HH + k];
                        ah = (_Float16)wv;
                        al = (_Float16)((wv - (float)ah) * LO_SCALE);
                    } else if (k == 61) {
                        al = (_Float16)(Lg * W_ih[ga * HH + ua]);
                    } else if (k == 62) {
                        const float bv = Lg * (b_ih[ga * HH + ua] + b_hh[ga * HH + ua]);
                        ah = (_Float16)bv;
                        al = (_Float16)((bv - (float)ah) * LO_SCALE);
                    } else if (k == 63) {
                        const float wv = Lg * W_ih[ga * HH + ua];
                        ah = (_Float16)wv;
                        al = (_Float16)((wv - (float)ah) * LO_SCALE);
                    }
                }
                vh[e] = ah; vl[e] = al;
            }
            Ah[tt][s] = vh; Al[tt][s] = vl;
        }
    }

    // ---- LDS pointers (u16 units; buffer = 1024 u16) ----
    // Read: lane's B0 at u16 idx 8*lane (bytes 16*lane); B1 at +512.
    const unsigned short* rbase = &hb[0][0] + 8 * lane;
    // Write: unit u, batch b -> idx 128*(u>>3) + 8*b + (u&7).
    //   u0 = 8w+hi -> 128w + 8*bcol + hi;  u1 = u0+4 -> +4.
    unsigned short* wb0 = &hb[0][0] + 128 * w + 8 * bcol + hi;
    const bool hw0 = (8 * w + hi) < HH;
    const bool hw1 = (8 * w + 4 + hi) < HH;
    // Aug (k=61,62,63): idx 896 + 8*b + {5,6,7}. Wave 7 (all-pad) writes.
    const bool xwriter = (w == 7) && (hi == 3);
    unsigned short* xwb = &hb[0][0] + 896 + 8 * bcol;
    const unsigned short one_us = F16BITS(1.0f);

    __syncthreads();   // staging + zero-init complete

    // ---- prologue: buf0 aug = (x_lo'(0), 1.0, x_hi(0)) ----
    if (xwriter) {
        const float x0 = xs[bcol * XP + 0];
        const _Float16 xh = (_Float16)x0;
        const _Float16 xl = (_Float16)((x0 - (float)xh) * LO_SCALE);
        *(unsigned*)(xwb + 6) =
            (unsigned)one_us | ((unsigned)__builtin_bit_cast(unsigned short, xh) << 16);
        xwb[5] = __builtin_bit_cast(unsigned short, xl);
    }

    float c0 = 0.0f, c1 = 0.0f, h0v = 0.0f, h1v = 0.0f;
    const f32x4 zero4 = {0.0f, 0.0f, 0.0f, 0.0f};

    __syncthreads();

    // merged-rcp LSTM cell (R9-verified algebra); rows pre-scaled by Lg
#define UPDATE(A, B2, CC, HO) { \
        const float v0 = fmaf((B2)[0], LO_ISCALE, (A)[0]); \
        const float v1 = fmaf((B2)[1], LO_ISCALE, (A)[1]); \
        const float v2 = fmaf((B2)[2], LO_ISCALE, (A)[2]); \
        const float v3 = fmaf((B2)[3], LO_ISCALE, (A)[3]); \
        const float E1 = __builtin_amdgcn_exp2f(v0);   /* i */ \
        const float E2 = __builtin_amdgcn_exp2f(v1);   /* f */ \
        const float G  = __builtin_amdgcn_exp2f(v2);   /* g */ \
        const float E4 = __builtin_amdgcn_exp2f(v3);   /* o */ \
        const float P1 = 1.0f + E1, P2 = 1.0f + E2; \
        const float PG = 1.0f + G,  P4 = 1.0f + E4; \
        const float MG = 1.0f - G; \
        const float N  = fmaf((CC) * P1, PG, MG * P2); \
        const float D  = (P1 * P2) * PG; \
        CC = N * __builtin_amdgcn_rcpf(D); \
        const float C5 = __builtin_amdgcn_exp2f(L2 * (CC)); \
        const float Q  = (1.0f + C5) * P4; \
        HO = (1.0f - C5) * __builtin_amdgcn_rcpf(Q); }

    // One step: read buf CB (h(t-1) + aug x(t)), write buf 1-CB, one barrier.
#define STEP(CB, T) { \
        const f16x8 B0 = *(const f16x8*)(rbase + (CB) * 1024); \
        const f16x8 B1 = *(const f16x8*)(rbase + (CB) * 1024 + 512); \
        f32x4 p0 = __builtin_amdgcn_mfma_f32_16x16x32_f16(Ah[0][0], B0, zero4, 0, 0, 0); \
        f32x4 q0 = __builtin_amdgcn_mfma_f32_16x16x32_f16(Al[0][0], B0, zero4, 0, 0, 0); \
        f32x4 p1 = __builtin_amdgcn_mfma_f32_16x16x32_f16(Ah[1][0], B0, zero4, 0, 0, 0); \
        f32x4 q1 = __builtin_amdgcn_mfma_f32_16x16x32_f16(Al[1][0], B0, zero4, 0, 0, 0); \
        p0 = __builtin_amdgcn_mfma_f32_16x16x32_f16(Ah[0][1], B1, p0, 0, 0, 0); \
        q0 = __builtin_amdgcn_mfma_f32_16x16x32_f16(Al[0][1], B1, q0, 0, 0, 0); \
        p1 = __builtin_amdgcn_mfma_f32_16x16x32_f16(Ah[1][1], B1, p1, 0, 0, 0); \
        q1 = __builtin_amdgcn_mfma_f32_16x16x32_f16(Al[1][1], B1, q1, 0, 0, 0); \
        UPDATE(p0, q0, c0, h0v) \
        UPDATE(p1, q1, c1, h1v) \
        if (hw0) wb0[(1 - (CB)) * 1024]     = F16BITS(h0v); \
        if (hw1) wb0[(1 - (CB)) * 1024 + 4] = F16BITS(h1v); \
        if (xwriter) { \
            const float xn = xs[bcol * XP + (T) + 1]; \
            const _Float16 xh = (_Float16)xn; \
            const _Float16 xl = (_Float16)((xn - (float)xh) * LO_SCALE); \
            *(unsigned*)(xwb + (1 - (CB)) * 1024 + 6) = \
                (unsigned)one_us | ((unsigned)__builtin_bit_cast(unsigned short, xh) << 16); \
            xwb[(1 - (CB)) * 1024 + 5] = __builtin_bit_cast(unsigned short, xl); \
        } \
        __syncthreads(); }

    #pragma unroll 1
    for (int t = 0; t < TT; t += 2) {
        STEP(0, t)
        STEP(1, t + 1)
    }
#undef STEP
#undef UPDATE

    // ---- epilogue: h_T dot fc_w (once) ----
    hfin[bcol][8 * w + hi]     = h0v;   // pad units hold exact 0
    hfin[bcol][8 * w + 4 + hi] = h1v;
    __syncthreads();
    if (tid < NB * 3) {
        const int b = tid / 3, o = tid % 3;
        float s = fc_b[o];
        for (int uu = 0; uu < HH; ++uu)
            s = fmaf(hfin[b][uu], fc_w[o * HH + uu], s);
        out[(b0 + b) * 3 + o] = s;
    }
}

extern "C" void kernel_launch(void* const* d_in, const int* in_sizes, int n_in,
                              void* d_out, int out_size, void* d_ws, size_t ws_size,
                              hipStream_t stream) {
    const float* x    = (const float*)d_in[0];
    const float* W_ih = (const float*)d_in[1];
    const float* W_hh = (const float*)d_in[2];
    const float* b_ih = (const float*)d_in[3];
    const float* b_hh = (const float*)d_in[4];
    const float* fc_w = (const float*)d_in[5];
    const float* fc_b = (const float*)d_in[6];
    float* out = (float*)d_out;

    dim3 grid(BB / NB);      // 128 blocks
    dim3 block(NW * 64);     // 512 threads = 8 waves (2 per SIMD)
    lstm_r13_kernel<<<grid, block, 0, stream>>>(x, W_ih, W_hh, b_ih, b_hh,
                                                fc_w, fc_b, out);
}